// Round 1
// baseline (89.591 us; speedup 1.0000x reference)
//
#include <hip/hip_runtime.h>

// All-pairs Morse force, N=4096, f32.
// V(r) = D*(exp(-2(r-r0)/w) - 2*exp(-(r-r0)/w)), F_i = sum_j -dV/dr * dx/r
// with w=0.5, D=1.0 => -dV/dr = (2D/w)*(e*e - e) = 4*(e*e - e), e = exp((r0-r)/0.5).
//
// Parallelization: grid = (N/BLOCK) i-tiles x (N/JCHUNK) j-slices.
// Each block stages JCHUNK j-particles in LDS; each thread owns one i and
// accumulates a partial force over the slice, committed with atomicAdd.

constexpr int NN     = 4096;
constexpr int BLOCK  = 256;
constexpr int JCHUNK = 128;   // j's per block => grid.y = 32 slices

__global__ __launch_bounds__(BLOCK) void morse_force_kernel(
    const float* __restrict__ pos,   // [N,3]
    const float* __restrict__ rad,   // [N]
    const int*   __restrict__ act,   // [N] 0/1
    float*       __restrict__ out)   // [N,3], pre-zeroed
{
    __shared__ float4 sj[JCHUNK];    // x,y,z,radius
    __shared__ int    sa[JCHUNK];    // active flag

    const int tid = threadIdx.x;
    const int i   = blockIdx.x * BLOCK + tid;
    const int j0  = blockIdx.y * JCHUNK;

    // my particle
    const float xi = pos[3*i+0];
    const float yi = pos[3*i+1];
    const float zi = pos[3*i+2];
    const float ri = rad[i];
    const int   ai = act[i];

    // stage j chunk into LDS (first JCHUNK threads)
    if (tid < JCHUNK) {
        const int j = j0 + tid;
        sj[tid] = make_float4(pos[3*j+0], pos[3*j+1], pos[3*j+2], rad[j]);
        sa[tid] = act[j];
    }
    __syncthreads();

    float fx = 0.f, fy = 0.f, fz = 0.f;

    #pragma unroll 4
    for (int t = 0; t < JCHUNK; ++t) {
        const float4 p = sj[t];              // broadcast read, conflict-free
        const float dx = xi - p.x;
        const float dy = yi - p.y;
        const float dz = zi - p.z;
        const float d2 = dx*dx + dy*dy + dz*dz;

        const bool m = (sa[t] != 0) && ((j0 + t) != i);

        const float r   = sqrtf(m ? d2 : 1.0f);      // safe sqrt like reference
        const float e   = expf((ri + p.w - r) * 2.0f); // exp(-(r-r0)/w), w=0.5
        const float mag = 4.0f * (e*e - e);            // (2D/w)*(e^2-e)
        const float s   = m ? (mag / r) : 0.0f;

        fx += s * dx;
        fy += s * dy;
        fz += s * dz;
    }

    if (ai) {
        atomicAdd(&out[3*i+0], fx);
        atomicAdd(&out[3*i+1], fy);
        atomicAdd(&out[3*i+2], fz);
    }
}

extern "C" void kernel_launch(void* const* d_in, const int* in_sizes, int n_in,
                              void* d_out, int out_size, void* d_ws, size_t ws_size,
                              hipStream_t stream) {
    const float* pos = (const float*)d_in[0];
    const float* rad = (const float*)d_in[1];
    const int*   act = (const int*)d_in[2];
    float*       out = (float*)d_out;

    // d_out is poisoned to 0xAA before every timed launch — zero it (graph-safe).
    hipMemsetAsync(d_out, 0, (size_t)out_size * sizeof(float), stream);

    dim3 grid(NN / BLOCK, NN / JCHUNK);
    morse_force_kernel<<<grid, BLOCK, 0, stream>>>(pos, rad, act, out);
}

// Round 6
// 73.171 us; speedup vs baseline: 1.2244x; 1.2244x over previous
//
#include <hip/hip_runtime.h>

// All-pairs Morse force, N=4096, f32.
// V(r) = D*(exp(-2(r-r0)/w) - 2*exp(-(r-r0)/w)), w=0.5, D=1.0
// F_i = sum_{j active, j!=i} 4*(e*e - e)/r * (x_i - x_j),  e = exp(2*(r0 - r))
//
// Fast-math formulation (per pair, ~15 VALU + 2 trans slots):
//   irv = v_rsq_f32(d2)            ; 1/r
//   r   = d2 * irv                 ; r  (diag: 0*inf = NaN -> masked to 0)
//   e   = v_exp_f32(kri + swj - K*r)  ; K = 2*log2(e), swj = K*rad_j (or -1e30 if j inactive)
//   em  = e*e - e                  ; fma
//   s   = em * irv  (zeroed when j==i)
//   f  += s * dx                   ; global x4 applied once at the end
//
// Grid: (N/BLOCK) i-tiles x (N/JCHUNK) j-slices; JCHUNK=64 -> 1024 blocks
// (4 blocks/CU, 16 waves/CU). Partial forces committed via atomicAdd (64
// adds per output cell -- negligible contention).

constexpr int   NN     = 4096;
constexpr int   BLOCK  = 256;
constexpr int   JCHUNK = 64;
constexpr float KEXP   = 2.8853900817779268f;  // 2 * log2(e)

static __device__ __forceinline__ float fast_rsq(float x) {
    float r;
    asm("v_rsq_f32 %0, %1" : "=v"(r) : "v"(x));
    return r;
}
static __device__ __forceinline__ float fast_exp2(float x) {
    float r;
    asm("v_exp_f32 %0, %1" : "=v"(r) : "v"(x));
    return r;
}

__global__ __launch_bounds__(BLOCK) void morse_force_kernel(
    const float* __restrict__ pos,   // [N,3]
    const float* __restrict__ rad,   // [N]
    const int*   __restrict__ act,   // [N] 0/1
    float*       __restrict__ out)   // [N,3], pre-zeroed
{
    __shared__ float4 sj[JCHUNK];    // x, y, z, K*rad (or -1e30 if inactive)

    const int tid = threadIdx.x;
    const int i   = blockIdx.x * BLOCK + tid;
    const int j0  = blockIdx.y * JCHUNK;

    // my particle
    const float xi  = pos[3*i+0];
    const float yi  = pos[3*i+1];
    const float zi  = pos[3*i+2];
    const float kri = KEXP * rad[i];
    const int   ai  = act[i];

    // stage j chunk into LDS; fold j-activity into the exp argument
    if (tid < JCHUNK) {
        const int j = j0 + tid;
        const float sw = act[j] ? (KEXP * rad[j]) : -1e30f;
        sj[tid] = make_float4(pos[3*j+0], pos[3*j+1], pos[3*j+2], sw);
    }
    __syncthreads();

    float fx = 0.f, fy = 0.f, fz = 0.f;

    #pragma unroll 16
    for (int t = 0; t < JCHUNK; ++t) {
        const float4 p = sj[t];               // broadcast read, conflict-free
        const float dx = xi - p.x;
        const float dy = yi - p.y;
        const float dz = zi - p.z;
        const float d2 = fmaf(dx, dx, fmaf(dy, dy, dz * dz));

        const float irv = fast_rsq(d2);       // 1/r   (diag: +inf)
        const float r   = d2 * irv;           // r     (diag: NaN)
        const float arg = fmaf(-KEXP, r, kri + p.w);
        const float e   = fast_exp2(arg);     // exp(2*(r0-r)); 0 if j inactive
        const float em  = fmaf(e, e, -e);     // e^2 - e
        float s = em * irv;                   // (e^2-e)/r
        if (j0 + t == i) s = 0.f;             // exclude diagonal (kills NaN)

        fx = fmaf(s, dx, fx);
        fy = fmaf(s, dy, fy);
        fz = fmaf(s, dz, fz);
    }

    if (ai) {
        atomicAdd(&out[3*i+0], 4.f * fx);
        atomicAdd(&out[3*i+1], 4.f * fy);
        atomicAdd(&out[3*i+2], 4.f * fz);
    }
}

extern "C" void kernel_launch(void* const* d_in, const int* in_sizes, int n_in,
                              void* d_out, int out_size, void* d_ws, size_t ws_size,
                              hipStream_t stream) {
    const float* pos = (const float*)d_in[0];
    const float* rad = (const float*)d_in[1];
    const int*   act = (const int*)d_in[2];
    float*       out = (float*)d_out;

    // d_out is poisoned to 0xAA before every timed launch — zero it (graph-safe).
    hipMemsetAsync(d_out, 0, (size_t)out_size * sizeof(float), stream);

    dim3 grid(NN / BLOCK, NN / JCHUNK);
    morse_force_kernel<<<grid, BLOCK, 0, stream>>>(pos, rad, act, out);
}

// Round 7
// 69.094 us; speedup vs baseline: 1.2967x; 1.0590x over previous
//
#include <hip/hip_runtime.h>

// All-pairs Morse force, N=4096, f32 — atomic-free, memset-free version.
// F_i = 4 * sum_{j active, j!=i} (e*e - e)/r * (x_i - x_j), e = exp(2*(r0-r))
//
// Each block owns TI=4 consecutive i's. Threads: il = tid&3 (which i),
// s = tid>>2 (j-slice 0..63). Thread (il,s) sums j = s + 64*k, k=0..63.
// j's staged through LDS in 4 chunks of 1024 (16 KB). Per wave the 16
// distinct b128 LDS reads are broadcast-by-4 with 2-way bank aliasing (free).
// Reduction: shuffle-xor over offsets 4..32, then a tiny LDS cross-wave sum;
// 4 threads store the final rows. No atomics, no output pre-zeroing.

constexpr int   NN     = 4096;
constexpr int   BLOCK  = 256;
constexpr int   TI     = 4;            // i's per block -> grid = 1024 blocks
constexpr int   SL     = BLOCK / TI;   // 64 j-slices
constexpr int   CHUNK  = 1024;         // j's per LDS stage (16 KB)
constexpr int   NCHUNK = NN / CHUNK;   // 4
constexpr int   IPC    = CHUNK / SL;   // 16 inner iters per chunk
constexpr float KEXP   = 2.8853900817779268f;  // 2 * log2(e)

static __device__ __forceinline__ float fast_rsq(float x) {
    float r;
    asm("v_rsq_f32 %0, %1" : "=v"(r) : "v"(x));
    return r;
}
static __device__ __forceinline__ float fast_exp2(float x) {
    float r;
    asm("v_exp_f32 %0, %1" : "=v"(r) : "v"(x));
    return r;
}

__global__ __launch_bounds__(BLOCK) void morse_force_kernel(
    const float* __restrict__ pos,   // [N,3]
    const float* __restrict__ rad,   // [N]
    const int*   __restrict__ act,   // [N] 0/1
    float*       __restrict__ out)   // [N,3]
{
    __shared__ float4 sj[CHUNK];                 // x, y, z, K*rad (-1e30 if inactive)
    __shared__ float  red[BLOCK/64][TI][3];      // cross-wave partials

    const int tid = threadIdx.x;
    const int il  = tid & (TI - 1);
    const int s   = tid >> 2;                    // j-slice
    const int i0  = blockIdx.x * TI;
    const int i   = i0 + il;

    const float xi  = pos[3*i+0];
    const float yi  = pos[3*i+1];
    const float zi  = pos[3*i+2];
    const float kri = KEXP * rad[i];

    float fx = 0.f, fy = 0.f, fz = 0.f;
    int jv = s;                                  // this thread's current j

    for (int c = 0; c < NCHUNK; ++c) {
        // ---- stage 1024 j's into LDS (4 float4 per thread) ----
        #pragma unroll
        for (int u = 0; u < CHUNK / BLOCK; ++u) {
            const int jj = tid + BLOCK * u;
            const int j  = c * CHUNK + jj;
            const float sw = act[j] ? (KEXP * rad[j]) : -1e30f;
            sj[jj] = make_float4(pos[3*j+0], pos[3*j+1], pos[3*j+2], sw);
        }
        __syncthreads();

        // ---- 16 strided pair-iterations: j = s + 64*kk within chunk ----
        #pragma unroll
        for (int kk = 0; kk < IPC; ++kk) {
            const float4 p = sj[s + SL * kk];
            const float dx = xi - p.x;
            const float dy = yi - p.y;
            const float dz = zi - p.z;
            const float d2 = fmaf(dx, dx, fmaf(dy, dy, dz * dz));

            const float irv = fast_rsq(d2);          // 1/r
            const float r   = d2 * irv;              // r (diag: NaN, masked below)
            const float arg = fmaf(-KEXP, r, kri + p.w);
            const float e   = fast_exp2(arg);        // 0 if j inactive
            const float em  = fmaf(e, e, -e);        // e^2 - e
            float sc = em * irv;
            if (jv == i) sc = 0.f;                   // diagonal (kills NaN)

            fx = fmaf(sc, dx, fx);
            fy = fmaf(sc, dy, fy);
            fz = fmaf(sc, dz, fz);
            jv += SL;
        }
        __syncthreads();
    }

    // ---- reduce across the 64 slices of each i ----
    // in-wave: lanes with same (tid&3) differ in bits 2..5
    #pragma unroll
    for (int off = TI; off < 64; off <<= 1) {
        fx += __shfl_xor(fx, off, 64);
        fy += __shfl_xor(fy, off, 64);
        fz += __shfl_xor(fz, off, 64);
    }
    const int w = tid >> 6;                          // wave id 0..3
    if ((tid & 63) < TI) {
        red[w][il][0] = fx;
        red[w][il][1] = fy;
        red[w][il][2] = fz;
    }
    __syncthreads();
    if (tid < TI) {
        float sx = 0.f, sy = 0.f, sz = 0.f;
        #pragma unroll
        for (int ww = 0; ww < BLOCK / 64; ++ww) {
            sx += red[ww][tid][0];
            sy += red[ww][tid][1];
            sz += red[ww][tid][2];
        }
        const int ii = i0 + tid;
        const float scale = act[ii] ? 4.f : 0.f;     // inactive i -> zero row
        out[3*ii+0] = scale * sx;
        out[3*ii+1] = scale * sy;
        out[3*ii+2] = scale * sz;
    }
}

extern "C" void kernel_launch(void* const* d_in, const int* in_sizes, int n_in,
                              void* d_out, int out_size, void* d_ws, size_t ws_size,
                              hipStream_t stream) {
    const float* pos = (const float*)d_in[0];
    const float* rad = (const float*)d_in[1];
    const int*   act = (const int*)d_in[2];
    float*       out = (float*)d_out;

    // Every output element is written unconditionally by its owning block:
    // no memset, no atomics — single dispatch.
    morse_force_kernel<<<dim3(NN / TI), BLOCK, 0, stream>>>(pos, rad, act, out);
}